// Round 9
// baseline (253.122 us; speedup 1.0000x reference)
//
#include <hip/hip_runtime.h>
#include <hip/hip_bf16.h>

// Problem dims (fixed by reference)
#define BB 8
#define NN 2048
#define DD 256
#define MM (BB * NN)   // 16384 rows
#define RPB 8          // rows per block in attn_agg

typedef __attribute__((ext_vector_type(8))) short bf16x8_t;  // 8 bf16 = 4 VGPRs
typedef __attribute__((ext_vector_type(4))) float f32x4_t;

// ---------------------------------------------------------------------------
// Kernel A: h = x @ W^T + b. fp32 inputs, converted to bf16 at LDS staging,
// bf16 MFMA w/ fp32 accumulate, h written as bf16 (workspace).
// grid (M/64, 256/64), block 256 (4 waves).
// ---------------------------------------------------------------------------
__global__ __launch_bounds__(256) void gemm_h(
    const float* __restrict__ x,     // [M,256] fp32
    const float* __restrict__ Wt,    // [256,256] fp32 row-major [out,in] (B^T form)
    const float* __restrict__ bias,  // [256] fp32
    __hip_bfloat16* __restrict__ h)  // [M,256] bf16
{
    __shared__ __hip_bfloat16 As[64][72];
    __shared__ __hip_bfloat16 Bs[64][72];

    const int tid  = threadIdx.x;
    const int r    = tid >> 2;          // 0..63 staging row
    const int cs   = (tid & 3) * 16;    // k-segment 0/16/32/48
    const int w    = tid >> 6;          // wave 0..3
    const int lane = tid & 63;
    const int m16  = lane & 15;
    const int quad = lane >> 4;
    const long rowBase = (long)blockIdx.x * 64;
    const int  colBase = blockIdx.y * 64;

    f32x4_t acc[4];
#pragma unroll
    for (int c = 0; c < 4; c++) acc[c] = (f32x4_t){0.f, 0.f, 0.f, 0.f};

    for (int k0 = 0; k0 < 256; k0 += 64) {
        const float4* ag = (const float4*)(x  + (rowBase + r) * 256 + k0 + cs);
        const float4* bg = (const float4*)(Wt + (long)(colBase + r) * 256 + k0 + cs);
        float4 av[4], bv[4];
#pragma unroll
        for (int q = 0; q < 4; q++) { av[q] = ag[q]; bv[q] = bg[q]; }

        __align__(16) __hip_bfloat16 ta[16], tb[16];
#pragma unroll
        for (int q = 0; q < 4; q++) {
            ta[q * 4 + 0] = __float2bfloat16(av[q].x);
            ta[q * 4 + 1] = __float2bfloat16(av[q].y);
            ta[q * 4 + 2] = __float2bfloat16(av[q].z);
            ta[q * 4 + 3] = __float2bfloat16(av[q].w);
            tb[q * 4 + 0] = __float2bfloat16(bv[q].x);
            tb[q * 4 + 1] = __float2bfloat16(bv[q].y);
            tb[q * 4 + 2] = __float2bfloat16(bv[q].z);
            tb[q * 4 + 3] = __float2bfloat16(bv[q].w);
        }

        __syncthreads();
        *(uint4*)&As[r][cs]     = *(uint4*)&ta[0];
        *(uint4*)&As[r][cs + 8] = *(uint4*)&ta[8];
        *(uint4*)&Bs[r][cs]     = *(uint4*)&tb[0];
        *(uint4*)&Bs[r][cs + 8] = *(uint4*)&tb[8];
        __syncthreads();

#pragma unroll
        for (int kk = 0; kk < 64; kk += 32) {
            bf16x8_t af = *(const bf16x8_t*)&As[w * 16 + m16][kk + quad * 8];
#pragma unroll
            for (int c = 0; c < 4; c++) {
                bf16x8_t bf = *(const bf16x8_t*)&Bs[c * 16 + m16][kk + quad * 8];
                acc[c] = __builtin_amdgcn_mfma_f32_16x16x32_bf16(af, bf, acc[c], 0, 0, 0);
            }
        }
    }

    // Epilogue: C/D layout col = lane&15 (N side), row = quad*4 + reg (M side)
#pragma unroll
    for (int c = 0; c < 4; c++) {
        const int col = colBase + c * 16 + m16;
        const float bv = bias[col];
#pragma unroll
        for (int reg = 0; reg < 4; reg++) {
            const long row = rowBase + w * 16 + quad * 4 + reg;
            h[row * 256 + col] = __float2bfloat16(acc[c][reg] + bv);
        }
    }
}

// ---------------------------------------------------------------------------
// Kernel B: per row: s1b = h@a1 + att_b ; t2 = mask ? h@a2 : -1e30.
// One wave per row. t2 folds the j-side mask so attn_agg's scan is branchless:
// sigmoid(si + (-1e30)) == rcp(+inf) == 0 exactly -> masked edges drop out.
// ---------------------------------------------------------------------------
struct __attribute__((aligned(8))) bf4 { __hip_bfloat16 v[4]; };

__global__ __launch_bounds__(256) void s_kernel(
    const __hip_bfloat16* __restrict__ h,
    const float* __restrict__ a1,
    const float* __restrict__ a2,
    const float* __restrict__ mask,
    const float* __restrict__ attb_p,
    float* __restrict__ s1b, float* __restrict__ t2)
{
    const int w = threadIdx.x >> 6;
    const int lane = threadIdx.x & 63;
    const long row = (long)blockIdx.x * 4 + w;

    bf4 hv = *(const bf4*)(h + row * 256 + lane * 4);
    float4 A1 = *(const float4*)(a1 + lane * 4);
    float4 A2 = *(const float4*)(a2 + lane * 4);
    const float h0 = __bfloat162float(hv.v[0]), h1 = __bfloat162float(hv.v[1]);
    const float h2 = __bfloat162float(hv.v[2]), h3 = __bfloat162float(hv.v[3]);
    float p1 = h0 * A1.x + h1 * A1.y + h2 * A1.z + h3 * A1.w;
    float p2 = h0 * A2.x + h1 * A2.y + h2 * A2.z + h3 * A2.w;
#pragma unroll
    for (int off = 32; off; off >>= 1) {
        p1 += __shfl_down(p1, off);
        p2 += __shfl_down(p2, off);
    }
    if (lane == 0) {
        s1b[row] = p1 + attb_p[0];
        t2[row]  = (mask[row] != 0.f) ? p2 : -1e30f;
    }
}

// ---------------------------------------------------------------------------
// Kernel C: sparse attention aggregate (v9 — persistent rows + prefetch).
// Grid 2048 blocks (exactly 8/CU), each handles 8 consecutive rows of one
// batch. Evidence basis: attn_agg floor (~61us) is insensitive to gather
// inst-count below ~74/block (R5 vs R8) -> the floor is per-block exposed
// latency (arg/cold-start + adj-load chain). v9 amortizes setup 8x, loads
// the row-invariant t2 slice ONCE into registers, and register-prefetches
// row r+1's adj during row r's scan+gather.
//  - scan (R5-proven): branchless sigmoid, exec-masked append.
//  - gather (R8): one wave-inst per neighbor (lane = 4 channels via uint2),
//    list split 4 ways across waves, cross-wave combine via s_part.
//  - per-row s_cnt[RPB] zeroed once -> no reset races; 2 barriers/row
//    (B1 publishes list+sums; B2 fences s_part AND s_j reuse).
// b = blockIdx & 7 keeps each batch's 1 MB h slice hot in one XCD's L2.
// ---------------------------------------------------------------------------
__global__ __launch_bounds__(256, 8) void attn_agg(
    const float* __restrict__ adj,
    const float* __restrict__ mask,
    const __hip_bfloat16* __restrict__ h,
    const float* __restrict__ s1b,
    const float* __restrict__ t2,
    float* __restrict__ out)
{
    __shared__ unsigned short s_j[2048];     // neighbor index j
    __shared__ float          s_w[2048];     // edge weight
    __shared__ float          s_part[4][DD]; // per-wave channel partials
    __shared__ int            s_cnt[RPB];
    __shared__ float          s_sum[4];

    const int tid  = threadIdx.x;
    const int wv   = tid >> 6;
    const int lane = tid & 63;
    const int b    = blockIdx.x & 7;
    const int ibase = (blockIdx.x >> 3) * RPB;
    const long mbase = (long)b * NN;
    const char* hb = (const char*)(h + mbase * 256);  // block-uniform -> SGPR base

    if (tid < RPB) s_cnt[tid] = 0;

    // row-invariant t2 slice: 8 fp32/thread, kept in registers for all rows
    const float4* trow = (const float4*)(t2 + mbase);
    const float4 T0 = trow[tid], T1 = trow[256 + tid];

    const float4* arow = (const float4*)(adj + (mbase + ibase) * NN);

    // row 0 state
    float  cmask = mask[mbase + ibase];
    float4 cA0, cA1;
    if (cmask != 0.f) { cA0 = arow[tid]; cA1 = arow[256 + tid]; }
    __syncthreads();   // s_cnt zeroing visible before any appends

    for (int r = 0; r < RPB; r++) {
        // prefetch next row's adj (gated on its mask) — hides the load chain
        float  nmask = 0.f;
        float4 nA0, nA1;
        if (r + 1 < RPB) {
            nmask = mask[mbase + ibase + r + 1];
            if (nmask != 0.f) {
                nA0 = arow[(r + 1) * 512 + tid];
                nA1 = arow[(r + 1) * 512 + 256 + tid];
            }
        }

        const long row = mbase + ibase + r;
        if (cmask != 0.f) {                    // block-uniform per row
            const float si = s1b[row];
            float lsum = 0.f;
#pragma unroll
            for (int g = 0; g < 2; g++) {
                const int jb = g * 1024 + tid * 4;
                const float av[4] = {g ? cA1.x : cA0.x, g ? cA1.y : cA0.y,
                                     g ? cA1.z : cA0.z, g ? cA1.w : cA0.w};
                const float tv[4] = {g ? T1.x : T0.x, g ? T1.y : T0.y,
                                     g ? T1.z : T0.z, g ? T1.w : T0.w};
#pragma unroll
                for (int e = 0; e < 4; e++) {
                    const float z   = si + tv[e];
                    const float sig = __builtin_amdgcn_rcpf(1.f + __expf(-z)); // rcp(inf)=0
                    const float wgt = av[e] * sig;
                    lsum += wgt;
                    if (wgt != 0.f) {          // exec-masked append
                        const int pos = atomicAdd(&s_cnt[r], 1);
                        s_j[pos] = (unsigned short)(jb + e);
                        s_w[pos] = wgt;
                    }
                }
            }

#pragma unroll
            for (int off = 32; off; off >>= 1) lsum += __shfl_down(lsum, off);
            if (lane == 0) s_sum[wv] = lsum;
            __syncthreads();                   // B1: list + sums published

            const float inv = 1.f / (s_sum[0] + s_sum[1] + s_sum[2] + s_sum[3] + 1e-8f);
            const int   cnt = s_cnt[r];

            // gather: wave wv takes quarter [ks,ke); lane owns channels [4l,4l+4)
            const int qs = ((cnt + 15) >> 4) << 2;
            const int ks = min(wv * qs, cnt);
            const int ke = min(ks + qs, cnt);
            const int loff = lane * 8;

            float c0 = 0.f, c1 = 0.f, c2 = 0.f, c3 = 0.f;
            int k = ks;
            for (; k + 8 <= ke; k += 8) {
                ushort4 ja  = *(const ushort4*)&s_j[k];
                ushort4 jb2 = *(const ushort4*)&s_j[k + 4];
                float4  wa  = *(const float4*)&s_w[k];
                float4  wb  = *(const float4*)&s_w[k + 4];
                uint2 u[8];
                u[0] = *(const uint2*)(hb + ((int)ja.x  << 9) + loff);
                u[1] = *(const uint2*)(hb + ((int)ja.y  << 9) + loff);
                u[2] = *(const uint2*)(hb + ((int)ja.z  << 9) + loff);
                u[3] = *(const uint2*)(hb + ((int)ja.w  << 9) + loff);
                u[4] = *(const uint2*)(hb + ((int)jb2.x << 9) + loff);
                u[5] = *(const uint2*)(hb + ((int)jb2.y << 9) + loff);
                u[6] = *(const uint2*)(hb + ((int)jb2.z << 9) + loff);
                u[7] = *(const uint2*)(hb + ((int)jb2.w << 9) + loff);
                const float ww[8] = {wa.x, wa.y, wa.z, wa.w, wb.x, wb.y, wb.z, wb.w};
#pragma unroll
                for (int q = 0; q < 8; q++) {
                    c0 += ww[q] * __uint_as_float(u[q].x << 16);
                    c1 += ww[q] * __uint_as_float(u[q].x & 0xffff0000u);
                    c2 += ww[q] * __uint_as_float(u[q].y << 16);
                    c3 += ww[q] * __uint_as_float(u[q].y & 0xffff0000u);
                }
            }
            for (; k + 4 <= ke; k += 4) {
                ushort4 ja = *(const ushort4*)&s_j[k];
                float4  wa = *(const float4*)&s_w[k];
                uint2 u[4];
                u[0] = *(const uint2*)(hb + ((int)ja.x << 9) + loff);
                u[1] = *(const uint2*)(hb + ((int)ja.y << 9) + loff);
                u[2] = *(const uint2*)(hb + ((int)ja.z << 9) + loff);
                u[3] = *(const uint2*)(hb + ((int)ja.w << 9) + loff);
                const float ww[4] = {wa.x, wa.y, wa.z, wa.w};
#pragma unroll
                for (int q = 0; q < 4; q++) {
                    c0 += ww[q] * __uint_as_float(u[q].x << 16);
                    c1 += ww[q] * __uint_as_float(u[q].x & 0xffff0000u);
                    c2 += ww[q] * __uint_as_float(u[q].y << 16);
                    c3 += ww[q] * __uint_as_float(u[q].y & 0xffff0000u);
                }
            }
            for (; k < ke; k++) {
                const int jj = s_j[k];
                const float wk = s_w[k];
                uint2 u = *(const uint2*)(hb + (jj << 9) + loff);
                c0 += wk * __uint_as_float(u.x << 16);
                c1 += wk * __uint_as_float(u.x & 0xffff0000u);
                c2 += wk * __uint_as_float(u.y << 16);
                c3 += wk * __uint_as_float(u.y & 0xffff0000u);
            }

            *(float4*)&s_part[wv][lane * 4] = make_float4(c0, c1, c2, c3);
            __syncthreads();                   // B2: s_part ready; fences s_j reuse

            const float total = s_part[0][tid] + s_part[1][tid]
                              + s_part[2][tid] + s_part[3][tid];
            out[row * 256 + tid] = total * inv;
        } else {
            out[row * 256 + tid] = 0.f;
        }

        cmask = nmask; cA0 = nA0; cA1 = nA1;
    }
}

// ---------------------------------------------------------------------------
extern "C" void kernel_launch(void* const* d_in, const int* in_sizes, int n_in,
                              void* d_out, int out_size, void* d_ws, size_t ws_size,
                              hipStream_t stream) {
    const float* x    = (const float*)d_in[0];
    const float* adj  = (const float*)d_in[1];
    const float* mask = (const float*)d_in[2];
    const float* W    = (const float*)d_in[3];
    const float* bias = (const float*)d_in[4];
    const float* a1   = (const float*)d_in[5];
    const float* a2   = (const float*)d_in[6];
    const float* attb = (const float*)d_in[7];
    float* out = (float*)d_out;

    // workspace: h bf16 [16384*256] (8 MB) | s1b fp32 [16384] | t2 fp32 [16384]
    __hip_bfloat16* h = (__hip_bfloat16*)d_ws;
    float* s1b = (float*)((char*)d_ws + (size_t)MM * DD * 2);
    float* t2  = s1b + MM;

    gemm_h<<<dim3(MM / 64, DD / 64), 256, 0, stream>>>(x, W, bias, h);
    s_kernel<<<MM / 4, 256, 0, stream>>>(h, a1, a2, mask, attb, s1b, t2);
    attn_agg<<<MM / RPB, 256, 0, stream>>>(adj, mask, h, s1b, t2, out);
}